// Round 4
// baseline (537.780 us; speedup 1.0000x reference)
//
#include <hip/hip_runtime.h>
#include <hip/hip_bf16.h>

#define N_VOX 120000

typedef __attribute__((ext_vector_type(8))) __bf16 bf16x8;
typedef __attribute__((ext_vector_type(4))) float floatx4;
using bf16 = __hip_bfloat16;

__device__ __forceinline__ float b2f(bf16 v) { return __bfloat162float(v); }
__device__ __forceinline__ bf16 f2b(float v) { return __float2bfloat16(v); }

// ---------------------------------------------------------------------------
// Gather-GEMM conv stage: tout[n,:] = lrelu( sum_k uin[nbr[n,k],:] @ W[k] )
// uin: [N_VOX+1, CIN] bf16, row N_VOX is all zeros (missing-neighbor pad).
// bpack: B fragments prepacked per (kstep, cotile, lane): [KSTEPS][NT][64][8].
// Each wave computes a 16-row M-tile across all COUT columns.
// A-frag (m89/m120 layout): lane holds A[m=lane&15][k=(lane>>4)*8+j] = 8
// contiguous channels of one gathered neighbor row -> one 16B load / k-step.
//
// R4 restructure: latency-bound fix. Hoist the 9 rulebook indices (1 latency
// hop), then issue ALL gather loads into a[KSTEPS] before any MFMA so the
// whole K-panel is in flight at once (MLP = KSTEPS instead of 1).
// ---------------------------------------------------------------------------
template<int CIN, int COUT, bool STATS>
__global__ __launch_bounds__(256) void conv_kernel(
    const bf16* __restrict__ uin,
    const int*  __restrict__ nbr,     // [N_VOX, 9]
    const bf16* __restrict__ bpack,
    bf16* __restrict__ tout,          // [N_VOX, COUT] (rows 0..N-1 only)
    float* __restrict__ stats)        // [2][64]: sum, sumsq
{
    constexpr int NT = COUT / 16;
    constexpr int K = 9 * CIN;
    constexpr int KSTEPS = (K + 31) / 32;

    const int lane = threadIdx.x & 63;
    const int wave = threadIdx.x >> 6;
    const int m    = lane & 15;
    const int quad = lane >> 4;
    const int rowbase = blockIdx.x * 64 + wave * 16;
    const int row_m = rowbase + m;    // row this lane gathers A for

    // 1) all 9 neighbor indices up front (independent loads, 1 latency hop)
    int idxs[9];
#pragma unroll
    for (int nb = 0; nb < 9; ++nb) idxs[nb] = nbr[row_m * 9 + nb];

    // 2) issue ALL K-panel gathers; KSTEPS loads in flight per lane
    bf16x8 a[KSTEPS];
#pragma unroll
    for (int t = 0; t < KSTEPS; ++t) {
        const int kb = (t * 4 + quad) * 8;
        int nb, cib;
        if constexpr (K % 32 != 0) {
            const bool valid = kb < K;     // tail: B is packed zero there
            nb  = valid ? kb / CIN : 0;
            cib = valid ? kb % CIN : 0;
        } else {
            nb  = kb / CIN;
            cib = kb % CIN;
        }
        a[t] = *reinterpret_cast<const bf16x8*>(uin + idxs[nb] * CIN + cib);
    }

    // 3) MFMA sweep (B loads stream from L1/L2, compiler pipelines them)
    floatx4 acc[NT];
#pragma unroll
    for (int c = 0; c < NT; ++c) acc[c] = (floatx4){0.f, 0.f, 0.f, 0.f};

    const bf16x8* bp = reinterpret_cast<const bf16x8*>(bpack);
#pragma unroll
    for (int t = 0; t < KSTEPS; ++t) {
#pragma unroll
        for (int c = 0; c < NT; ++c) {
            const bf16x8 b = bp[(t * NT + c) * 64 + lane];
            acc[c] = __builtin_amdgcn_mfma_f32_16x16x32_bf16(a[t], b, acc[c], 0, 0, 0);
        }
    }

    // Epilogue: leaky-relu, store bf16, optional per-channel sum/sumsq stats.
    // C/D layout (m89): col(ch) = lane&15, row = quad*4 + reg.
    __shared__ float sS[64];
    __shared__ float sS2[64];
    if constexpr (STATS) {
        for (int i = threadIdx.x; i < COUT; i += 256) { sS[i] = 0.f; sS2[i] = 0.f; }
        __syncthreads();
    }
#pragma unroll
    for (int c = 0; c < NT; ++c) {
        const int ch = c * 16 + m;
        float ps = 0.f, ps2 = 0.f;
#pragma unroll
        for (int i = 0; i < 4; ++i) {
            const int r = rowbase + quad * 4 + i;
            float v = acc[c][i];
            v = v > 0.f ? v : 0.01f * v;
            tout[r * COUT + ch] = f2b(v);
            ps += v; ps2 += v * v;
        }
        if constexpr (STATS) {
            atomicAdd(&sS[ch], ps);
            atomicAdd(&sS2[ch], ps2);
        }
    }
    if constexpr (STATS) {
        __syncthreads();
        for (int i = threadIdx.x; i < COUT; i += 256) {
            atomicAdd(&stats[i],      sS[i]);
            atomicAdd(&stats[64 + i], sS2[i]);
        }
    }
}

// ---------------------------------------------------------------------------
// In-place BN affine on t[N_VOX,C] (bf16), writes zero pad row N_VOX.
// g, b are float32 (reference dtype).
// ---------------------------------------------------------------------------
template<int C>
__global__ __launch_bounds__(256) void bnapply_kernel(
    bf16* t, const float* __restrict__ s,
    const float* __restrict__ g, const float* __restrict__ b)
{
    const int idx = blockIdx.x * 256 + threadIdx.x;
    if (idx >= (N_VOX + 1) * C) return;
    if (idx >= N_VOX * C) { t[idx] = f2b(0.f); return; }
    const int ch = idx & (C - 1);
    const float inv_n = 1.0f / N_VOX;
    const float mu = s[ch] * inv_n;
    const float var = fmaxf(s[64 + ch] * inv_n - mu * mu, 0.f);
    const float a = rsqrtf(var + 1e-5f) * g[ch];
    const float c0 = b[ch] - mu * a;
    t[idx] = f2b(a * b2f(t[idx]) + c0);
}

// ---------------------------------------------------------------------------
// out = BN_a(ta) + BN_b(tb); OUT = bf16 (intermediate y, with zero pad row)
// or float (final d_out). Elementwise in-place safe for same-width types.
// ---------------------------------------------------------------------------
template<int C, bool ZROW, typename OUT>
__global__ __launch_bounds__(256) void addbn_kernel(
    const bf16* ta, const float* __restrict__ sa,
    const float* __restrict__ ga, const float* __restrict__ ba,
    const bf16* tb, const float* __restrict__ sb,
    const float* __restrict__ gb, const float* __restrict__ bb,
    OUT* out)
{
    const int total = (N_VOX + (ZROW ? 1 : 0)) * C;
    const int idx = blockIdx.x * 256 + threadIdx.x;
    if (idx >= total) return;
    if (ZROW && idx >= N_VOX * C) { out[idx] = (OUT)0.f; return; }
    const int ch = idx & (C - 1);
    const float inv_n = 1.0f / N_VOX;
    const float ma = sa[ch] * inv_n;
    const float va = fmaxf(sa[64 + ch] * inv_n - ma * ma, 0.f);
    const float aa = rsqrtf(va + 1e-5f) * ga[ch];
    const float ca = ba[ch] - ma * aa;
    const float mb = sb[ch] * inv_n;
    const float vb = fmaxf(sb[64 + ch] * inv_n - mb * mb, 0.f);
    const float ab = rsqrtf(vb + 1e-5f) * gb[ch];
    const float cb = bb[ch] - mb * ab;
    const float v = aa * b2f(ta[idx]) + ca + ab * b2f(tb[idx]) + cb;
    if constexpr (sizeof(OUT) == 2) out[idx] = f2b(v);
    else                            out[idx] = v;
}

// ---------------------------------------------------------------------------
// Prep (single kernel, regions by global id):
//  1) u0 = bf16(x) with zero pad row          [x is float32 per reference]
//  2) pack all 8 weights (float32) into bf16 MFMA B-fragment order:
//     B[k = t*32 + (lane>>4)*8 + j][n = c*16 + (lane&15)], zeros for k >= 9*CIN
//  3) zero stats buffers + zero pad row of u3
// ---------------------------------------------------------------------------
#define PACK_TOTAL 139264
__global__ __launch_bounds__(256) void prep_kernel(
    const float* __restrict__ x,
    const float* W0, const float* W1, const float* W2, const float* W3,
    const float* W4, const float* W5, const float* W6, const float* W7,
    bf16* __restrict__ u0, bf16* __restrict__ bpack,
    float* __restrict__ stats, bf16* __restrict__ u3)
{
    const int gid = blockIdx.x * 256 + threadIdx.x;
    constexpr int NXE = (N_VOX + 1) * 16;
    if (gid < NXE) {
        u0[gid] = (gid < N_VOX * 16) ? f2b(x[gid]) : f2b(0.f);
        return;
    }
    int p = gid - NXE;
    if (p < PACK_TOTAL) {
        constexpr int cin[8]  = {16, 32, 16, 32, 32, 64, 32, 64};
        constexpr int cout[8] = {32, 32, 32, 32, 64, 64, 64, 64};
        constexpr int offs[9] = {0, 5120, 14336, 19456, 28672, 47104, 83968, 102400, 139264};
        const float* Ws[8] = {W0, W1, W2, W3, W4, W5, W6, W7};
        int w = 0;
        while (p >= offs[w + 1]) ++w;
        const int e = p - offs[w];
        const int CI = cin[w], CO = cout[w];
        const int NTl = CO / 16;
        const int j = e & 7;
        const int lane = (e >> 3) & 63;
        const int rest = e >> 9;
        const int c = rest % NTl;
        const int t = rest / NTl;
        const int ncol = c * 16 + (lane & 15);
        const int k = t * 32 + (lane >> 4) * 8 + j;
        float val = 0.f;
        if (k < 9 * CI) {
            const int nbq = k / CI;
            const int ci = k % CI;
            val = Ws[w][(nbq * CI + ci) * CO + ncol];
        }
        bpack[p] = f2b(val);
        return;
    }
    p -= PACK_TOTAL;
    if (p < 1024) { stats[p] = 0.f; return; }
    p -= 1024;
    if (p < 32) u3[N_VOX * 32 + p] = f2b(0.f);
}

extern "C" void kernel_launch(void* const* d_in, const int* in_sizes, int n_in,
                              void* d_out, int out_size, void* d_ws, size_t ws_size,
                              hipStream_t stream) {
    // Reference dtypes: all float tensors are float32; rulebooks int32.
    const float* x     = (const float*)d_in[0];
    const int* nbr133  = (const int*)d_in[1];
    const int* nbr313  = (const int*)d_in[2];
    const float* W_c1  = (const float*)d_in[3];
    const float* g0    = (const float*)d_in[4];
    const float* b0    = (const float*)d_in[5];
    const float* W_c12 = (const float*)d_in[6];
    const float* g02   = (const float*)d_in[7];
    const float* b02   = (const float*)d_in[8];
    const float* W_c2  = (const float*)d_in[9];
    const float* W_c3  = (const float*)d_in[10];
    const float* g2    = (const float*)d_in[11];
    const float* b2    = (const float*)d_in[12];
    const float* W_r1  = (const float*)d_in[13];
    const float* rg0   = (const float*)d_in[14];
    const float* rb0   = (const float*)d_in[15];
    const float* W_r12 = (const float*)d_in[16];
    const float* rg02  = (const float*)d_in[17];
    const float* rb02  = (const float*)d_in[18];
    const float* W_r2  = (const float*)d_in[19];
    const float* rg1   = (const float*)d_in[20];
    const float* rb1   = (const float*)d_in[21];
    const float* W_r3  = (const float*)d_in[22];
    const float* rg2   = (const float*)d_in[23];
    const float* rb2   = (const float*)d_in[24];

    // --- workspace layout with aliasing; peak ~58 MB --------------------------
    // Def-use schedule (single stream, sequential):
    //   prep:  u0, bpack, stats, u3-pad
    //   conv1: u0 -> B1(R1);  bnapply B1 (+pad)
    //   conv2: B1 -> T2(R3)
    //   conv3: u0 -> u3(R1)   [B1 dead, same buffer; pad row still zero]
    //   conv4: u3 -> T4(R2)
    //   addbn1: T2,T4 -> uy(R3 in-place, bf16, +pad)   [u0,u3,T4 dead after]
    //   conv5: uy -> B5(R4);  bnapply B5 (+pad)
    //   conv6: B5 -> T6 (aliases R0+R1+R2 head region, 19.2MB >= 15.36MB)
    //   conv7: uy -> B7(R4)   [B5 dead];  bnapply B7 (+pad)
    //   conv8: B7 -> T8(R5, bf16)
    //   addbn2: T6,T8 -> d_out (float32)
    char* ws = (char*)d_ws;
    size_t off = 0;
    auto alloc = [&](size_t bytes) -> char* {
        off = (off + 255) & ~(size_t)255;
        char* p = ws + off;
        off += bytes;
        return p;
    };
    const size_t NV = N_VOX;
    bf16* u0   = (bf16*)alloc((NV + 1) * 16 * 2);   // R0: bf16(x) padded; later part of T6
    bf16* B1u3 = (bf16*)alloc((NV + 1) * 32 * 2);   // R1: B1 then u3; later part of T6
    bf16* T4   = (bf16*)alloc(NV * 32 * 2);         // R2: later part of T6
    bf16* T2uy = (bf16*)alloc((NV + 1) * 32 * 2);   // R3: T2 then uy (in-place addbn)
    bf16* B5B7 = (bf16*)alloc((NV + 1) * 64 * 2);   // R4: B5 then B7
    bf16* T8   = (bf16*)alloc(NV * 64 * 2);         // R5
    bf16* bpack = (bf16*)alloc((size_t)PACK_TOTAL * 2);
    float* stats = (float*)alloc(1024 * 4);         // 8 slots x [sum[64], sumsq[64]]
    bf16* T6 = (bf16*)ws;                           // alias R0..R2 (19.2MB available)

    float* st1 = stats + 0 * 128;
    float* st2 = stats + 1 * 128;
    float* st4 = stats + 3 * 128;
    float* st5 = stats + 4 * 128;
    float* st6 = stats + 5 * 128;
    float* st7 = stats + 6 * 128;
    float* st8 = stats + 7 * 128;

    bf16* bp0 = bpack + 0;       // W_c1  (16->32)
    bf16* bp1 = bpack + 5120;    // W_c12 (32->32)
    bf16* bp2 = bpack + 14336;   // W_c2  (16->32)
    bf16* bp3 = bpack + 19456;   // W_c3  (32->32)
    bf16* bp4 = bpack + 28672;   // W_r1  (32->64)
    bf16* bp5 = bpack + 47104;   // W_r12 (64->64)
    bf16* bp6 = bpack + 83968;   // W_r2  (32->64)
    bf16* bp7 = bpack + 102400;  // W_r3  (64->64)

    const int prep_total = (N_VOX + 1) * 16 + PACK_TOTAL + 1024 + 32;
    prep_kernel<<<(prep_total + 255) / 256, 256, 0, stream>>>(
        x, W_c1, W_c12, W_c2, W_c3, W_r1, W_r12, W_r2, W_r3, u0, bpack, stats, B1u3);

    const int CB = N_VOX / 64;  // 1875, exact
    const int E32 = ((N_VOX + 1) * 32 + 255) / 256;
    const int E64 = ((N_VOX + 1) * 64 + 255) / 256;

    // ResContextBlock
    conv_kernel<16, 32, true><<<CB, 256, 0, stream>>>(u0, nbr133, bp0, B1u3, st1);
    bnapply_kernel<32><<<E32, 256, 0, stream>>>(B1u3, st1, g0, b0);
    conv_kernel<32, 32, true><<<CB, 256, 0, stream>>>(B1u3, nbr313, bp1, T2uy, st2);
    conv_kernel<16, 32, false><<<CB, 256, 0, stream>>>(u0, nbr313, bp2, B1u3, nullptr);
    conv_kernel<32, 32, true><<<CB, 256, 0, stream>>>(B1u3, nbr133, bp3, T4, st4);
    addbn_kernel<32, true, bf16><<<E32, 256, 0, stream>>>(
        T2uy, st2, g02, b02, T4, st4, g2, b2, T2uy);
    // ResBlock
    conv_kernel<32, 64, true><<<CB, 256, 0, stream>>>(T2uy, nbr313, bp4, B5B7, st5);
    bnapply_kernel<64><<<E64, 256, 0, stream>>>(B5B7, st5, rg0, rb0);
    conv_kernel<64, 64, true><<<CB, 256, 0, stream>>>(B5B7, nbr133, bp5, T6, st6);
    conv_kernel<32, 64, true><<<CB, 256, 0, stream>>>(T2uy, nbr133, bp6, B5B7, st7);
    bnapply_kernel<64><<<E64, 256, 0, stream>>>(B5B7, st7, rg1, rb1);
    conv_kernel<64, 64, true><<<CB, 256, 0, stream>>>(B5B7, nbr313, bp7, T8, st8);
    addbn_kernel<64, false, float><<<(N_VOX * 64 + 255) / 256, 256, 0, stream>>>(
        T6, st6, rg02, rb02, T8, st8, rg2, rb2, (float*)d_out);
}

// Round 5
// 444.183 us; speedup vs baseline: 1.2107x; 1.2107x over previous
//
#include <hip/hip_runtime.h>
#include <hip/hip_bf16.h>

#define N_VOX 120000
#define GRID_G 1024   // 4 blocks/CU x 256 CUs, all resident (LDS <= 37.4 KB)

typedef __attribute__((ext_vector_type(8))) __bf16 bf16x8;
typedef __attribute__((ext_vector_type(4))) float floatx4;
using bf16 = __hip_bfloat16;

__device__ __forceinline__ float b2f(bf16 v) { return __bfloat162float(v); }
__device__ __forceinline__ bf16 f2b(float v) { return __float2bfloat16(v); }

// Async 16B gather direct to LDS. No VGPR destination -> the compiler cannot
// sink it to the use site (R4 failure mode). lds dest = uniform base + lane*16.
__device__ __forceinline__ void gload_lds16(const bf16* g, bf16* l) {
    __builtin_amdgcn_global_load_lds(
        (const __attribute__((address_space(1))) void*)g,
        (__attribute__((address_space(3))) void*)l, 16, 0, 0);
}

// ---------------------------------------------------------------------------
// Gather-GEMM conv: tout[n,:] = lrelu( sum_k uin[nbr[n,k],:] @ W[k] )
// Grid-stride over M-tiles; per block-iter stage TM*16 rows' full K-panel in
// LDS (double-buffered, async gathers overlap previous tile's compute).
// Wave roles: COUT=64 (TM=1): wave ci=w owns cols [16ci,16ci+16) of the tile.
//             COUT=32 (TM=2): mi=w>>1, ci=w&1.
// B-fragments: loaded ONCE per block into VGPRs (KSTEPS x 4 regs), reused for
// all tiles. A-frag for lane: its own gathered 16 B (identity LDS readback).
// ---------------------------------------------------------------------------
template<int CIN, int COUT, int TM, bool STATS>
__global__ __launch_bounds__(256) void conv_kernel(
    const bf16* __restrict__ uin,     // [N_VOX+1, CIN], pad row zero
    const int*  __restrict__ nbr,     // [N_VOX, 9]
    const bf16* __restrict__ bpack,   // prepacked B frags
    bf16* __restrict__ tout,          // [N_VOX, COUT]
    float* __restrict__ stats)        // [sum[64], sumsq[64]]
{
    constexpr int NT = COUT / 16;
    constexpr int K = 9 * CIN;
    constexpr int KSTEPS = (K + 31) / 32;
    constexpr int SPT = TM * KSTEPS;                 // ksteps staged per tile
    constexpr int ITERS_TOTAL = N_VOX / (TM * 16);   // exact (7500 / 3750)

    __shared__ __align__(16) bf16 As[2][SPT * 512];  // [buf][kstep][lane*8]
    __shared__ float sS[64], sS2[64];

    const int lane = threadIdx.x & 63;
    const int wave = threadIdx.x >> 6;
    const int m    = lane & 15;
    const int quad = lane >> 4;
    const int mi = (TM == 1) ? 0 : (wave >> 1);
    const int ci = (TM == 1) ? wave : (wave & 1);

    if (STATS && threadIdx.x < 64) { sS[threadIdx.x] = 0.f; sS2[threadIdx.x] = 0.f; }

    // B fragments once per block (<=72 VGPRs)
    bf16x8 Bf[KSTEPS];
    const bf16x8* bp = reinterpret_cast<const bf16x8*>(bpack);
#pragma unroll
    for (int t = 0; t < KSTEPS; ++t) Bf[t] = bp[(t * NT + ci) * 64 + lane];

    const int G = gridDim.x;
    const int nIter = (ITERS_TOTAL + G - 1) / G;

    auto issue = [&](int it, int bu) {
        const int tb = it * G + blockIdx.x;
        if (tb >= ITERS_TOTAL) return;
        const int rowb = tb * (TM * 16);
        for (int s = wave; s < SPT; s += 4) {       // ksteps striped over waves
            const int mi2 = s / KSTEPS;
            const int tt  = s % KSTEPS;
            const int kb = (tt * 4 + quad) * 8;
            int nb, cib;
            if (kb < K) { nb = kb / CIN; cib = kb % CIN; }
            else        { nb = 0;        cib = 0; }    // tail: B packed zero
            const int row = rowb + mi2 * 16 + m;
            const int idx = nbr[row * 9 + nb];         // == N_VOX if missing
            gload_lds16(uin + (size_t)idx * CIN + cib, &As[bu][s * 512]);
        }
    };

    int bu = 0;
    issue(0, 0);
    for (int it = 0; it < nIter; ++it) {
        __syncthreads();              // drains vmcnt: buf[bu] gathers complete
        issue(it + 1, bu ^ 1);        // prefetch overlaps compute below
        const int tb = it * G + blockIdx.x;
        if (tb < ITERS_TOTAL) {
            const int rowb = tb * (TM * 16) + mi * 16;
            floatx4 acc = {0.f, 0.f, 0.f, 0.f};
            const bf16x8* ap = reinterpret_cast<const bf16x8*>(&As[bu][mi * KSTEPS * 512]);
#pragma unroll
            for (int tt = 0; tt < KSTEPS; ++tt)
                acc = __builtin_amdgcn_mfma_f32_16x16x32_bf16(ap[tt * 64 + lane], Bf[tt], acc, 0, 0, 0);
            // epilogue: C/D layout col=lane&15, row=quad*4+i
            const int ch = ci * 16 + m;
            float ps = 0.f, ps2 = 0.f;
#pragma unroll
            for (int i = 0; i < 4; ++i) {
                float v = acc[i];
                v = v > 0.f ? v : 0.01f * v;
                tout[(size_t)(rowb + quad * 4 + i) * COUT + ch] = f2b(v);
                ps += v; ps2 += v * v;
            }
            if (STATS) { atomicAdd(&sS[ch], ps); atomicAdd(&sS2[ch], ps2); }
        }
        bu ^= 1;
    }
    if (STATS) {
        __syncthreads();
        if (threadIdx.x < COUT) {
            atomicAdd(&stats[threadIdx.x],      sS[threadIdx.x]);
            atomicAdd(&stats[64 + threadIdx.x], sS2[threadIdx.x]);
        }
    }
}

// ---------------------------------------------------------------------------
// In-place BN affine on t[N_VOX,C] (bf16) + zero pad row. Per-channel affine
// precomputed into LDS once per block; main loop = 16B load + 16B store.
// ---------------------------------------------------------------------------
template<int C>
__global__ __launch_bounds__(256) void bnapply_kernel(
    bf16* t, const float* __restrict__ s,
    const float* __restrict__ g, const float* __restrict__ b)
{
    __shared__ float pa[64], pc[64];
    if (threadIdx.x < C) {
        const float inv_n = 1.0f / N_VOX;
        const float mu = s[threadIdx.x] * inv_n;
        const float var = fmaxf(s[64 + threadIdx.x] * inv_n - mu * mu, 0.f);
        const float a = rsqrtf(var + 1e-5f) * g[threadIdx.x];
        pa[threadIdx.x] = a;
        pc[threadIdx.x] = b[threadIdx.x] - mu * a;
    }
    __syncthreads();
    const int i8 = (blockIdx.x * 256 + threadIdx.x) * 8;
    if (i8 >= (N_VOX + 1) * C) return;
    if (i8 >= N_VOX * C) {                      // pad row -> zeros
        uint4 z = {0, 0, 0, 0};
        *reinterpret_cast<uint4*>(t + i8) = z;
        return;
    }
    union { bf16x8 v; bf16 e[8]; } U, O;
    U.v = *reinterpret_cast<const bf16x8*>(t + i8);
    const int ch0 = i8 & (C - 1);
#pragma unroll
    for (int j = 0; j < 8; ++j)
        O.e[j] = f2b(pa[ch0 + j] * b2f(U.e[j]) + pc[ch0 + j]);
    *reinterpret_cast<bf16x8*>(t + i8) = O.v;
}

// ---------------------------------------------------------------------------
// out = BN_a(ta) + BN_b(tb); OUT = bf16 (intermediate y, +zero pad row) or
// float (final d_out). Elementwise in-place safe.
// ---------------------------------------------------------------------------
template<int C, bool ZROW, typename OUT>
__global__ __launch_bounds__(256) void addbn_kernel(
    const bf16* ta, const float* __restrict__ sa,
    const float* __restrict__ ga, const float* __restrict__ ba,
    const bf16* tb, const float* __restrict__ sb,
    const float* __restrict__ gb, const float* __restrict__ bb,
    OUT* out)
{
    __shared__ float paa[64], pca[64], pab[64], pcb[64];
    if (threadIdx.x < C) {
        const float inv_n = 1.0f / N_VOX;
        const float ma = sa[threadIdx.x] * inv_n;
        const float va = fmaxf(sa[64 + threadIdx.x] * inv_n - ma * ma, 0.f);
        const float aa = rsqrtf(va + 1e-5f) * ga[threadIdx.x];
        paa[threadIdx.x] = aa;
        pca[threadIdx.x] = ba[threadIdx.x] - ma * aa;
        const float mb = sb[threadIdx.x] * inv_n;
        const float vb = fmaxf(sb[64 + threadIdx.x] * inv_n - mb * mb, 0.f);
        const float ab = rsqrtf(vb + 1e-5f) * gb[threadIdx.x];
        pab[threadIdx.x] = ab;
        pcb[threadIdx.x] = bb[threadIdx.x] - mb * ab;
    }
    __syncthreads();
    constexpr int TOTAL = (N_VOX + (ZROW ? 1 : 0)) * C;
    const int i8 = (blockIdx.x * 256 + threadIdx.x) * 8;
    if (i8 >= TOTAL) return;
    if (ZROW && i8 >= N_VOX * C) {
        uint4 z = {0, 0, 0, 0};
        *reinterpret_cast<uint4*>((bf16*)out + i8) = z;
        return;
    }
    union { bf16x8 v; bf16 e[8]; } A, B;
    A.v = *reinterpret_cast<const bf16x8*>(ta + i8);
    B.v = *reinterpret_cast<const bf16x8*>(tb + i8);
    const int ch0 = i8 & (C - 1);
    float r[8];
#pragma unroll
    for (int j = 0; j < 8; ++j)
        r[j] = paa[ch0 + j] * b2f(A.e[j]) + pca[ch0 + j]
             + pab[ch0 + j] * b2f(B.e[j]) + pcb[ch0 + j];
    if constexpr (sizeof(OUT) == 2) {
        union { bf16x8 v; bf16 e[8]; } O;
#pragma unroll
        for (int j = 0; j < 8; ++j) O.e[j] = f2b(r[j]);
        *reinterpret_cast<bf16x8*>(out + i8) = O.v;
    } else {
#pragma unroll
        for (int j = 0; j < 8; ++j) out[i8 + j] = r[j];
    }
}

// ---------------------------------------------------------------------------
// Prep: u0 = bf16(x) + zero pad row; pack 8 weights (f32) into bf16 MFMA
// B-fragment order B[k = t*32+(lane>>4)*8+j][n = c*16+(lane&15)] (zeros for
// k >= 9*CIN); zero stats; zero pad row of u3.
// ---------------------------------------------------------------------------
#define PACK_TOTAL 139264
__global__ __launch_bounds__(256) void prep_kernel(
    const float* __restrict__ x,
    const float* W0, const float* W1, const float* W2, const float* W3,
    const float* W4, const float* W5, const float* W6, const float* W7,
    bf16* __restrict__ u0, bf16* __restrict__ bpack,
    float* __restrict__ stats, bf16* __restrict__ u3)
{
    const int gid = blockIdx.x * 256 + threadIdx.x;
    constexpr int NXE = (N_VOX + 1) * 16;
    if (gid < NXE) {
        u0[gid] = (gid < N_VOX * 16) ? f2b(x[gid]) : f2b(0.f);
        return;
    }
    int p = gid - NXE;
    if (p < PACK_TOTAL) {
        constexpr int cin[8]  = {16, 32, 16, 32, 32, 64, 32, 64};
        constexpr int cout[8] = {32, 32, 32, 32, 64, 64, 64, 64};
        constexpr int offs[9] = {0, 5120, 14336, 19456, 28672, 47104, 83968, 102400, 139264};
        const float* Ws[8] = {W0, W1, W2, W3, W4, W5, W6, W7};
        int w = 0;
        while (p >= offs[w + 1]) ++w;
        const int e = p - offs[w];
        const int CI = cin[w], CO = cout[w];
        const int NTl = CO / 16;
        const int j = e & 7;
        const int lane = (e >> 3) & 63;
        const int rest = e >> 9;
        const int c = rest % NTl;
        const int t = rest / NTl;
        const int ncol = c * 16 + (lane & 15);
        const int k = t * 32 + (lane >> 4) * 8 + j;
        float val = 0.f;
        if (k < 9 * CI) {
            const int nbq = k / CI;
            const int ci = k % CI;
            val = Ws[w][(nbq * CI + ci) * CO + ncol];
        }
        bpack[p] = f2b(val);
        return;
    }
    p -= PACK_TOTAL;
    if (p < 1024) { stats[p] = 0.f; return; }
    p -= 1024;
    if (p < 32) u3[N_VOX * 32 + p] = f2b(0.f);
}

extern "C" void kernel_launch(void* const* d_in, const int* in_sizes, int n_in,
                              void* d_out, int out_size, void* d_ws, size_t ws_size,
                              hipStream_t stream) {
    const float* x     = (const float*)d_in[0];
    const int* nbr133  = (const int*)d_in[1];
    const int* nbr313  = (const int*)d_in[2];
    const float* W_c1  = (const float*)d_in[3];
    const float* g0    = (const float*)d_in[4];
    const float* b0    = (const float*)d_in[5];
    const float* W_c12 = (const float*)d_in[6];
    const float* g02   = (const float*)d_in[7];
    const float* b02   = (const float*)d_in[8];
    const float* W_c2  = (const float*)d_in[9];
    const float* W_c3  = (const float*)d_in[10];
    const float* g2    = (const float*)d_in[11];
    const float* b2    = (const float*)d_in[12];
    const float* W_r1  = (const float*)d_in[13];
    const float* rg0   = (const float*)d_in[14];
    const float* rb0   = (const float*)d_in[15];
    const float* W_r12 = (const float*)d_in[16];
    const float* rg02  = (const float*)d_in[17];
    const float* rb02  = (const float*)d_in[18];
    const float* W_r2  = (const float*)d_in[19];
    const float* rg1   = (const float*)d_in[20];
    const float* rb1   = (const float*)d_in[21];
    const float* W_r3  = (const float*)d_in[22];
    const float* rg2   = (const float*)d_in[23];
    const float* rb2   = (const float*)d_in[24];

    // Workspace aliasing schedule identical to R3 (passed correctness):
    //   conv1: u0 -> B1(R1); bn B1 | conv2: B1 -> T2(R3) | conv3: u0 -> u3(R1)
    //   conv4: u3 -> T4(R2) | addbn1: T2,T4 -> uy(R3 in place)
    //   conv5: uy -> B5(R4); bn | conv6: B5 -> T6(=ws head, R0..R2 dead)
    //   conv7: uy -> B7(R4); bn | conv8: B7 -> T8(R5) | addbn2 -> d_out (f32)
    char* ws = (char*)d_ws;
    size_t off = 0;
    auto alloc = [&](size_t bytes) -> char* {
        off = (off + 255) & ~(size_t)255;
        char* p = ws + off;
        off += bytes;
        return p;
    };
    const size_t NV = N_VOX;
    bf16* u0   = (bf16*)alloc((NV + 1) * 16 * 2);
    bf16* B1u3 = (bf16*)alloc((NV + 1) * 32 * 2);
    bf16* T4   = (bf16*)alloc(NV * 32 * 2);
    bf16* T2uy = (bf16*)alloc((NV + 1) * 32 * 2);
    bf16* B5B7 = (bf16*)alloc((NV + 1) * 64 * 2);
    bf16* T8   = (bf16*)alloc(NV * 64 * 2);
    bf16* bpack = (bf16*)alloc((size_t)PACK_TOTAL * 2);
    float* stats = (float*)alloc(1024 * 4);
    bf16* T6 = (bf16*)ws;    // alias R0..R2 (19.2 MB available >= 15.36 MB)

    float* st1 = stats + 0 * 128;
    float* st2 = stats + 1 * 128;
    float* st4 = stats + 3 * 128;
    float* st5 = stats + 4 * 128;
    float* st6 = stats + 5 * 128;
    float* st7 = stats + 6 * 128;
    float* st8 = stats + 7 * 128;

    bf16* bp0 = bpack + 0;       // W_c1  (16->32)
    bf16* bp1 = bpack + 5120;    // W_c12 (32->32)
    bf16* bp2 = bpack + 14336;   // W_c2  (16->32)
    bf16* bp3 = bpack + 19456;   // W_c3  (32->32)
    bf16* bp4 = bpack + 28672;   // W_r1  (32->64)
    bf16* bp5 = bpack + 47104;   // W_r12 (64->64)
    bf16* bp6 = bpack + 83968;   // W_r2  (32->64)
    bf16* bp7 = bpack + 102400;  // W_r3  (64->64)

    const int prep_total = (N_VOX + 1) * 16 + PACK_TOTAL + 1024 + 32;
    prep_kernel<<<(prep_total + 255) / 256, 256, 0, stream>>>(
        x, W_c1, W_c12, W_c2, W_c3, W_r1, W_r12, W_r2, W_r3, u0, bpack, stats, B1u3);

    const int E32 = (((N_VOX + 1) * 32) / 8 + 255) / 256;
    const int E64 = (((N_VOX + 1) * 64) / 8 + 255) / 256;

    // ResContextBlock
    conv_kernel<16, 32, 2, true><<<GRID_G, 256, 0, stream>>>(u0, nbr133, bp0, B1u3, st1);
    bnapply_kernel<32><<<E32, 256, 0, stream>>>(B1u3, st1, g0, b0);
    conv_kernel<32, 32, 2, true><<<GRID_G, 256, 0, stream>>>(B1u3, nbr313, bp1, T2uy, st2);
    conv_kernel<16, 32, 2, false><<<GRID_G, 256, 0, stream>>>(u0, nbr313, bp2, B1u3, nullptr);
    conv_kernel<32, 32, 2, true><<<GRID_G, 256, 0, stream>>>(B1u3, nbr133, bp3, T4, st4);
    addbn_kernel<32, true, bf16><<<E32, 256, 0, stream>>>(
        T2uy, st2, g02, b02, T4, st4, g2, b2, T2uy);
    // ResBlock
    conv_kernel<32, 64, 1, true><<<GRID_G, 256, 0, stream>>>(T2uy, nbr313, bp4, B5B7, st5);
    bnapply_kernel<64><<<E64, 256, 0, stream>>>(B5B7, st5, rg0, rb0);
    conv_kernel<64, 64, 1, true><<<GRID_G, 256, 0, stream>>>(B5B7, nbr133, bp5, T6, st6);
    conv_kernel<32, 64, 1, true><<<GRID_G, 256, 0, stream>>>(T2uy, nbr133, bp6, B5B7, st7);
    bnapply_kernel<64><<<E64, 256, 0, stream>>>(B5B7, st7, rg1, rb1);
    conv_kernel<64, 64, 1, true><<<GRID_G, 256, 0, stream>>>(B5B7, nbr313, bp7, T8, st8);
    addbn_kernel<64, false, float><<<((N_VOX * 64 / 8) + 255) / 256, 256, 0, stream>>>(
        T6, st6, rg02, rb02, T8, st8, rg2, rb2, (float*)d_out);
}

// Round 6
// 332.701 us; speedup vs baseline: 1.6164x; 1.3351x over previous
//
#include <hip/hip_runtime.h>
#include <hip/hip_bf16.h>

#define N_VOX 120000
#define NTILES (N_VOX / 16)   // 7500
#define CONV_GRID 512         // 2 blocks/CU; all resident even at 74 KB LDS

typedef __attribute__((ext_vector_type(8))) __bf16 bf16x8;
typedef __attribute__((ext_vector_type(4))) float floatx4;
using bf16 = __hip_bfloat16;

__device__ __forceinline__ float b2f(bf16 v) { return __bfloat162float(v); }
__device__ __forceinline__ bf16 f2b(float v) { return __float2bfloat16(v); }

// Inline-asm 16B global load: opaque to the compiler's scheduler, so the
// KSTEPS gathers stay batched (R4: VGPR-dest C loads get sunk to use sites;
// R5: LDS-dest loads got serialized behind idx chains + barrier drains).
__device__ __forceinline__ bf16x8 gload16(const bf16* p) {
    bf16x8 r;
    asm volatile("global_load_dwordx4 %0, %1, off" : "=v"(r) : "v"(p));
    return r;
}
__device__ __forceinline__ void vm_wait0() {
    asm volatile("s_waitcnt vmcnt(0)" ::: "memory");
}
// Redefine value after the waitcnt so MFMAs can't be hoisted above it.
__device__ __forceinline__ void pin(bf16x8& x) {
    asm volatile("" : "+v"(x));
}

// ---------------------------------------------------------------------------
// Gather-GEMM conv: tout[n,:] = lrelu( sum_k uin[nbr[n,k],:] @ W[k] )
// One wave per 16-row tile, ALL COUT columns; grid-stride; no K-loop barriers.
// A-frag (m89): lane holds A[m=lane&15][k=quad*8+j] -> 16B of one row.
// B-frags: VGPRs if COUT==32 (<=18 frags), LDS-staged once if COUT==64.
// ---------------------------------------------------------------------------
template<int CIN, int COUT, bool STATS>
__global__ __launch_bounds__(256) void conv_kernel(
    const bf16* __restrict__ uin,     // [N_VOX+1, CIN], pad row zero
    const int*  __restrict__ nbr,     // [N_VOX, 9]
    const bf16* __restrict__ bpack,   // prepacked B frags
    bf16* __restrict__ tout,          // [N_VOX, COUT]
    float* __restrict__ stats)        // [sum[64], sumsq[64]]
{
    constexpr int NT = COUT / 16;
    constexpr int K = 9 * CIN;
    constexpr int KSTEPS = (K + 31) / 32;
    constexpr bool BLDS = (COUT == 64);
    constexpr int NFRAG = KSTEPS * NT;

    __shared__ bf16x8 Bs[BLDS ? NFRAG * 64 : 1];
    __shared__ float sS[64], sS2[64];

    const int lane = threadIdx.x & 63;
    const int wave = threadIdx.x >> 6;
    const int m    = lane & 15;
    const int quad = lane >> 4;

    if (STATS && threadIdx.x < 64) { sS[threadIdx.x] = 0.f; sS2[threadIdx.x] = 0.f; }

    const bf16x8* bp = reinterpret_cast<const bf16x8*>(bpack);
    bf16x8 Bf[BLDS ? 1 : NFRAG];
    if constexpr (BLDS) {
        for (int f = threadIdx.x; f < NFRAG * 64; f += 256) Bs[f] = bp[f];
    } else {
#pragma unroll
        for (int f = 0; f < NFRAG; ++f) Bf[f] = bp[f * 64 + lane];
    }
    __syncthreads();

    float ssum[NT], ssum2[NT];
#pragma unroll
    for (int c = 0; c < NT; ++c) { ssum[c] = 0.f; ssum2[c] = 0.f; }

    const int GW = gridDim.x * 4;
    for (int tile = blockIdx.x * 4 + wave; tile < NTILES; tile += GW) {
        const int row = tile * 16 + m;
        int idx[9];
#pragma unroll
        for (int nb = 0; nb < 9; ++nb) idx[nb] = nbr[row * 9 + nb];

        bf16x8 a[KSTEPS];
#pragma unroll
        for (int t = 0; t < KSTEPS; ++t) {
            const bf16* src;
            if constexpr (CIN == 64) {
                src = uin + (((size_t)idx[t >> 1]) << 6) + ((t & 1) << 5) + quad * 8;
            } else if constexpr (CIN == 32) {
                src = uin + (((size_t)idx[t]) << 5) + quad * 8;
            } else {  // CIN == 16: nb = 2t + (quad>>1); tail t=4 quads 2,3 -> pad
                constexpr int KS = 9 * 16;
                const int j1 = (2 * t + 1 > 8) ? 8 : 2 * t + 1;
                int r_ = (quad & 2) ? idx[j1] : idx[2 * t];
                if (t * 32 + 24 >= KS) {           // tail kstep only
                    if (t * 32 + quad * 8 >= KS) r_ = N_VOX;
                }
                src = uin + (((size_t)r_) << 4) + ((quad & 1) << 3);
            }
            a[t] = gload16(src);
        }
        vm_wait0();
#pragma unroll
        for (int t = 0; t < KSTEPS; ++t) pin(a[t]);

        floatx4 acc[NT];
#pragma unroll
        for (int c = 0; c < NT; ++c) acc[c] = (floatx4){0.f, 0.f, 0.f, 0.f};
#pragma unroll
        for (int t = 0; t < KSTEPS; ++t) {
#pragma unroll
            for (int c = 0; c < NT; ++c) {
                const bf16x8 b = BLDS ? Bs[(t * NT + c) * 64 + lane] : Bf[t * NT + c];
                acc[c] = __builtin_amdgcn_mfma_f32_16x16x32_bf16(a[t], b, acc[c], 0, 0, 0);
            }
        }
        // epilogue: C/D layout col=lane&15, row=quad*4+i
#pragma unroll
        for (int c = 0; c < NT; ++c) {
            const int ch = c * 16 + m;
            float ps = 0.f, ps2 = 0.f;
#pragma unroll
            for (int i = 0; i < 4; ++i) {
                float v = acc[c][i];
                v = v > 0.f ? v : 0.01f * v;
                tout[(size_t)(tile * 16 + quad * 4 + i) * COUT + ch] = f2b(v);
                ps += v; ps2 += v * v;
            }
            ssum[c] += ps; ssum2[c] += ps2;
        }
    }

    if constexpr (STATS) {
#pragma unroll
        for (int c = 0; c < NT; ++c) {
            atomicAdd(&sS[c * 16 + m], ssum[c]);
            atomicAdd(&sS2[c * 16 + m], ssum2[c]);
        }
        __syncthreads();
        if (threadIdx.x < COUT) {
            atomicAdd(&stats[threadIdx.x],      sS[threadIdx.x]);
            atomicAdd(&stats[64 + threadIdx.x], sS2[threadIdx.x]);
        }
    }
}

// ---------------------------------------------------------------------------
// In-place BN affine on t[N_VOX,C] (bf16) + zero pad row.
// ---------------------------------------------------------------------------
template<int C>
__global__ __launch_bounds__(256) void bnapply_kernel(
    bf16* t, const float* __restrict__ s,
    const float* __restrict__ g, const float* __restrict__ b)
{
    __shared__ float pa[64], pc[64];
    if (threadIdx.x < C) {
        const float inv_n = 1.0f / N_VOX;
        const float mu = s[threadIdx.x] * inv_n;
        const float var = fmaxf(s[64 + threadIdx.x] * inv_n - mu * mu, 0.f);
        const float a = rsqrtf(var + 1e-5f) * g[threadIdx.x];
        pa[threadIdx.x] = a;
        pc[threadIdx.x] = b[threadIdx.x] - mu * a;
    }
    __syncthreads();
    const int i8 = (blockIdx.x * 256 + threadIdx.x) * 8;
    if (i8 >= (N_VOX + 1) * C) return;
    if (i8 >= N_VOX * C) {
        uint4 z = {0, 0, 0, 0};
        *reinterpret_cast<uint4*>(t + i8) = z;
        return;
    }
    union { bf16x8 v; bf16 e[8]; } U, O;
    U.v = *reinterpret_cast<const bf16x8*>(t + i8);
    const int ch0 = i8 & (C - 1);
#pragma unroll
    for (int j = 0; j < 8; ++j)
        O.e[j] = f2b(pa[ch0 + j] * b2f(U.e[j]) + pc[ch0 + j]);
    *reinterpret_cast<bf16x8*>(t + i8) = O.v;
}

// ---------------------------------------------------------------------------
// out = BN_a(ta) + BN_b(tb); OUT bf16 (+pad row) or float (final).
// ---------------------------------------------------------------------------
template<int C, bool ZROW, typename OUT>
__global__ __launch_bounds__(256) void addbn_kernel(
    const bf16* ta, const float* __restrict__ sa,
    const float* __restrict__ ga, const float* __restrict__ ba,
    const bf16* tb, const float* __restrict__ sb,
    const float* __restrict__ gb, const float* __restrict__ bb,
    OUT* out)
{
    __shared__ float paa[64], pca[64], pab[64], pcb[64];
    if (threadIdx.x < C) {
        const float inv_n = 1.0f / N_VOX;
        const float ma = sa[threadIdx.x] * inv_n;
        const float va = fmaxf(sa[64 + threadIdx.x] * inv_n - ma * ma, 0.f);
        const float aa = rsqrtf(va + 1e-5f) * ga[threadIdx.x];
        paa[threadIdx.x] = aa;
        pca[threadIdx.x] = ba[threadIdx.x] - ma * aa;
        const float mb = sb[threadIdx.x] * inv_n;
        const float vb = fmaxf(sb[64 + threadIdx.x] * inv_n - mb * mb, 0.f);
        const float ab = rsqrtf(vb + 1e-5f) * gb[threadIdx.x];
        pab[threadIdx.x] = ab;
        pcb[threadIdx.x] = bb[threadIdx.x] - mb * ab;
    }
    __syncthreads();
    constexpr int TOTAL = (N_VOX + (ZROW ? 1 : 0)) * C;
    const int i8 = (blockIdx.x * 256 + threadIdx.x) * 8;
    if (i8 >= TOTAL) return;
    if (ZROW && i8 >= N_VOX * C) {
        uint4 z = {0, 0, 0, 0};
        *reinterpret_cast<uint4*>((bf16*)out + i8) = z;
        return;
    }
    union { bf16x8 v; bf16 e[8]; } A, B;
    A.v = *reinterpret_cast<const bf16x8*>(ta + i8);
    B.v = *reinterpret_cast<const bf16x8*>(tb + i8);
    const int ch0 = i8 & (C - 1);
    float r[8];
#pragma unroll
    for (int j = 0; j < 8; ++j)
        r[j] = paa[ch0 + j] * b2f(A.e[j]) + pca[ch0 + j]
             + pab[ch0 + j] * b2f(B.e[j]) + pcb[ch0 + j];
    if constexpr (sizeof(OUT) == 2) {
        union { bf16x8 v; bf16 e[8]; } O;
#pragma unroll
        for (int j = 0; j < 8; ++j) O.e[j] = f2b(r[j]);
        *reinterpret_cast<bf16x8*>(out + i8) = O.v;
    } else {
#pragma unroll
        for (int j = 0; j < 8; ++j) out[i8 + j] = r[j];
    }
}

// ---------------------------------------------------------------------------
// Prep: u0 = bf16(x) + zero pad row; pack 8 f32 weights into bf16 MFMA
// B-fragment order B[k=t*32+(lane>>4)*8+j][n=c*16+(lane&15)] (zero for k>=K);
// zero stats; zero pad row of u3.
// ---------------------------------------------------------------------------
#define PACK_TOTAL 139264
__global__ __launch_bounds__(256) void prep_kernel(
    const float* __restrict__ x,
    const float* W0, const float* W1, const float* W2, const float* W3,
    const float* W4, const float* W5, const float* W6, const float* W7,
    bf16* __restrict__ u0, bf16* __restrict__ bpack,
    float* __restrict__ stats, bf16* __restrict__ u3)
{
    const int gid = blockIdx.x * 256 + threadIdx.x;
    constexpr int NXE = (N_VOX + 1) * 16;
    if (gid < NXE) {
        u0[gid] = (gid < N_VOX * 16) ? f2b(x[gid]) : f2b(0.f);
        return;
    }
    int p = gid - NXE;
    if (p < PACK_TOTAL) {
        constexpr int cin[8]  = {16, 32, 16, 32, 32, 64, 32, 64};
        constexpr int cout[8] = {32, 32, 32, 32, 64, 64, 64, 64};
        constexpr int offs[9] = {0, 5120, 14336, 19456, 28672, 47104, 83968, 102400, 139264};
        const float* Ws[8] = {W0, W1, W2, W3, W4, W5, W6, W7};
        int w = 0;
        while (p >= offs[w + 1]) ++w;
        const int e = p - offs[w];
        const int CI = cin[w], CO = cout[w];
        const int NTl = CO / 16;
        const int j = e & 7;
        const int lane = (e >> 3) & 63;
        const int rest = e >> 9;
        const int c = rest % NTl;
        const int t = rest / NTl;
        const int ncol = c * 16 + (lane & 15);
        const int k = t * 32 + (lane >> 4) * 8 + j;
        float val = 0.f;
        if (k < 9 * CI) {
            const int nbq = k / CI;
            const int ci = k % CI;
            val = Ws[w][(nbq * CI + ci) * CO + ncol];
        }
        bpack[p] = f2b(val);
        return;
    }
    p -= PACK_TOTAL;
    if (p < 1024) { stats[p] = 0.f; return; }
    p -= 1024;
    if (p < 32) u3[N_VOX * 32 + p] = f2b(0.f);
}

extern "C" void kernel_launch(void* const* d_in, const int* in_sizes, int n_in,
                              void* d_out, int out_size, void* d_ws, size_t ws_size,
                              hipStream_t stream) {
    const float* x     = (const float*)d_in[0];
    const int* nbr133  = (const int*)d_in[1];
    const int* nbr313  = (const int*)d_in[2];
    const float* W_c1  = (const float*)d_in[3];
    const float* g0    = (const float*)d_in[4];
    const float* b0    = (const float*)d_in[5];
    const float* W_c12 = (const float*)d_in[6];
    const float* g02   = (const float*)d_in[7];
    const float* b02   = (const float*)d_in[8];
    const float* W_c2  = (const float*)d_in[9];
    const float* W_c3  = (const float*)d_in[10];
    const float* g2    = (const float*)d_in[11];
    const float* b2    = (const float*)d_in[12];
    const float* W_r1  = (const float*)d_in[13];
    const float* rg0   = (const float*)d_in[14];
    const float* rb0   = (const float*)d_in[15];
    const float* W_r12 = (const float*)d_in[16];
    const float* rg02  = (const float*)d_in[17];
    const float* rb02  = (const float*)d_in[18];
    const float* W_r2  = (const float*)d_in[19];
    const float* rg1   = (const float*)d_in[20];
    const float* rb1   = (const float*)d_in[21];
    const float* W_r3  = (const float*)d_in[22];
    const float* rg2   = (const float*)d_in[23];
    const float* rb2   = (const float*)d_in[24];

    // Workspace aliasing schedule identical to R3/R5 (correctness-proven).
    char* ws = (char*)d_ws;
    size_t off = 0;
    auto alloc = [&](size_t bytes) -> char* {
        off = (off + 255) & ~(size_t)255;
        char* p = ws + off;
        off += bytes;
        return p;
    };
    const size_t NV = N_VOX;
    bf16* u0   = (bf16*)alloc((NV + 1) * 16 * 2);
    bf16* B1u3 = (bf16*)alloc((NV + 1) * 32 * 2);
    bf16* T4   = (bf16*)alloc(NV * 32 * 2);
    bf16* T2uy = (bf16*)alloc((NV + 1) * 32 * 2);
    bf16* B5B7 = (bf16*)alloc((NV + 1) * 64 * 2);
    bf16* T8   = (bf16*)alloc(NV * 64 * 2);
    bf16* bpack = (bf16*)alloc((size_t)PACK_TOTAL * 2);
    float* stats = (float*)alloc(1024 * 4);
    bf16* T6 = (bf16*)ws;    // alias R0..R2 (19.2 MB available >= 15.36 MB)

    float* st1 = stats + 0 * 128;
    float* st2 = stats + 1 * 128;
    float* st4 = stats + 3 * 128;
    float* st5 = stats + 4 * 128;
    float* st6 = stats + 5 * 128;
    float* st7 = stats + 6 * 128;
    float* st8 = stats + 7 * 128;

    bf16* bp0 = bpack + 0;       // W_c1  (16->32)
    bf16* bp1 = bpack + 5120;    // W_c12 (32->32)
    bf16* bp2 = bpack + 14336;   // W_c2  (16->32)
    bf16* bp3 = bpack + 19456;   // W_c3  (32->32)
    bf16* bp4 = bpack + 28672;   // W_r1  (32->64)
    bf16* bp5 = bpack + 47104;   // W_r12 (64->64)
    bf16* bp6 = bpack + 83968;   // W_r2  (32->64)
    bf16* bp7 = bpack + 102400;  // W_r3  (64->64)

    const int prep_total = (N_VOX + 1) * 16 + PACK_TOTAL + 1024 + 32;
    prep_kernel<<<(prep_total + 255) / 256, 256, 0, stream>>>(
        x, W_c1, W_c12, W_c2, W_c3, W_r1, W_r12, W_r2, W_r3, u0, bpack, stats, B1u3);

    const int E32 = (((N_VOX + 1) * 32) / 8 + 255) / 256;
    const int E64 = (((N_VOX + 1) * 64) / 8 + 255) / 256;

    // ResContextBlock
    conv_kernel<16, 32, true><<<CONV_GRID, 256, 0, stream>>>(u0, nbr133, bp0, B1u3, st1);
    bnapply_kernel<32><<<E32, 256, 0, stream>>>(B1u3, st1, g0, b0);
    conv_kernel<32, 32, true><<<CONV_GRID, 256, 0, stream>>>(B1u3, nbr313, bp1, T2uy, st2);
    conv_kernel<16, 32, false><<<CONV_GRID, 256, 0, stream>>>(u0, nbr313, bp2, B1u3, nullptr);
    conv_kernel<32, 32, true><<<CONV_GRID, 256, 0, stream>>>(B1u3, nbr133, bp3, T4, st4);
    addbn_kernel<32, true, bf16><<<E32, 256, 0, stream>>>(
        T2uy, st2, g02, b02, T4, st4, g2, b2, T2uy);
    // ResBlock
    conv_kernel<32, 64, true><<<CONV_GRID, 256, 0, stream>>>(T2uy, nbr313, bp4, B5B7, st5);
    bnapply_kernel<64><<<E64, 256, 0, stream>>>(B5B7, st5, rg0, rb0);
    conv_kernel<64, 64, true><<<CONV_GRID, 256, 0, stream>>>(B5B7, nbr133, bp5, T6, st6);
    conv_kernel<32, 64, true><<<CONV_GRID, 256, 0, stream>>>(T2uy, nbr133, bp6, B5B7, st7);
    bnapply_kernel<64><<<E64, 256, 0, stream>>>(B5B7, st7, rg1, rb1);
    conv_kernel<64, 64, true><<<CONV_GRID, 256, 0, stream>>>(B5B7, nbr313, bp7, T8, st8);
    addbn_kernel<64, false, float><<<((N_VOX * 64 / 8) + 255) / 256, 256, 0, stream>>>(
        T6, st6, rg02, rb02, T8, st8, rg2, rb2, (float*)d_out);
}

// Round 7
// 316.699 us; speedup vs baseline: 1.6981x; 1.0505x over previous
//
#include <hip/hip_runtime.h>
#include <hip/hip_bf16.h>

#define N_VOX 120000
#define NTILES (N_VOX / 16)   // 7500

typedef __attribute__((ext_vector_type(8))) __bf16 bf16x8;
typedef __attribute__((ext_vector_type(4))) float floatx4;
using bf16 = __hip_bfloat16;

__device__ __forceinline__ float b2f(bf16 v) { return __bfloat162float(v); }
__device__ __forceinline__ bf16 f2b(float v) { return __float2bfloat16(v); }

// All VMEM in the conv K-loop is inline asm: (a) compiler cannot sink/split
// the batched gathers (R4 failure), (b) vmcnt bookkeeping is deterministic,
// enabling cross-tile prefetch with exact s_waitcnt immediates.
__device__ __forceinline__ bf16x8 gload16(const bf16* p) {
    bf16x8 r;
    asm volatile("global_load_dwordx4 %0, %1, off" : "=v"(r) : "v"(p));
    return r;
}
__device__ __forceinline__ int gloadi(const int* p) {
    int r;
    asm volatile("global_load_dword %0, %1, off" : "=v"(r) : "v"(p));
    return r;
}
__device__ __forceinline__ void gstore16(bf16* p, bf16x8 v) {
    asm volatile("global_store_dwordx4 %0, %1, off" :: "v"(p), "v"(v) : "memory");
}
__device__ __forceinline__ void vm_wait0() { asm volatile("s_waitcnt vmcnt(0)" ::: "memory"); }
__device__ __forceinline__ void vm_wait1() { asm volatile("s_waitcnt vmcnt(1)" ::: "memory"); }
__device__ __forceinline__ void vm_wait2() { asm volatile("s_waitcnt vmcnt(2)" ::: "memory"); }
__device__ __forceinline__ void vm_wait3() { asm volatile("s_waitcnt vmcnt(3)" ::: "memory"); }
__device__ __forceinline__ void pin(bf16x8& x) { asm volatile("" : "+v"(x)); }
__device__ __forceinline__ void pini(int& x)   { asm volatile("" : "+v"(x)); }

// ---------------------------------------------------------------------------
// Gather-GEMM conv: tout[n,:] = lrelu( sum_k uin[nbr[n,k],:] @ W[k] )
// One wave per 16-row tile, all COUT cols; grid-stride; no in-loop barriers.
// TA-minimized: idx loads coalesced via LDS (prefetched 1 tile ahead),
// C-tile transposed through wave-private LDS -> 1-2 coalesced dwordx4 stores.
// ---------------------------------------------------------------------------
template<int CIN, int COUT, int NW, bool STATS>
__global__ __launch_bounds__(NW * 64) void conv_kernel(
    const bf16* __restrict__ uin,     // [N_VOX+1, CIN], pad row zero
    const int*  __restrict__ nbr,     // [N_VOX, 9]
    const bf16* __restrict__ bpack,   // prepacked B frags
    bf16* __restrict__ tout,          // [N_VOX, COUT]
    float* __restrict__ stats)        // [sum[64], sumsq[64]]
{
    constexpr int NT = COUT / 16;
    constexpr int K = 9 * CIN;
    constexpr int KSTEPS = (K + 31) / 32;
    constexpr bool BLDS = (COUT == 64);
    constexpr int NFRAG = KSTEPS * NT;
    constexpr int NSTORE = (16 * COUT) / 512;   // 1 (COUT=32) or 2 (COUT=64)

    __shared__ bf16x8 Bs[BLDS ? NFRAG * 64 : 1];
    __shared__ int idxb[NW][2][192];
    __shared__ __align__(16) bf16 tbuf[NW][16 * COUT];
    __shared__ float sS[64], sS2[64];

    const int lane = threadIdx.x & 63;
    const int wave = threadIdx.x >> 6;
    const int m    = lane & 15;
    const int quad = lane >> 4;

    if (STATS && threadIdx.x < 64) { sS[threadIdx.x] = 0.f; sS2[threadIdx.x] = 0.f; }

    const bf16x8* bp = reinterpret_cast<const bf16x8*>(bpack);
    bf16x8 Bf[BLDS ? 1 : NFRAG];
    if constexpr (BLDS) {
        for (int f = threadIdx.x; f < NFRAG * 64; f += NW * 64) Bs[f] = bp[f];
    } else {
#pragma unroll
        for (int f = 0; f < NFRAG; ++f) Bf[f] = bp[f * 64 + lane];
    }
    __syncthreads();

    float ssum[NT], ssum2[NT];
#pragma unroll
    for (int c = 0; c < NT; ++c) { ssum[c] = 0.f; ssum2[c] = 0.f; }

    const int STRIDE = gridDim.x * NW;
    const int t0 = blockIdx.x * NW + wave;      // < NTILES by grid construction

    // Prologue: coalesced idx load for tile t0 (144 contiguous dwords).
    {
        const int* b0 = nbr + t0 * 144;
        int i0 = gloadi(b0 + lane);
        int i1 = gloadi(b0 + 64 + lane);
        int i2 = gloadi(b0 + 128 + (lane & 15));
        vm_wait0();
        pini(i0); pini(i1); pini(i2);
        int* ib = idxb[wave][0];
        ib[lane] = i0; ib[64 + lane] = i1; ib[128 + (lane & 15)] = i2;
    }

    int p = 0;
    for (int tile = t0; tile < NTILES; tile += STRIDE) {
        // 1) per-lane idx from LDS (no TA traffic)
        const int* ib = idxb[wave][p];
        int idx[9];
#pragma unroll
        for (int nb = 0; nb < 9; ++nb) idx[nb] = ib[m * 9 + nb];

        // 2) issue all K-panel gathers (asm, batched)
        bf16x8 a[KSTEPS];
#pragma unroll
        for (int t = 0; t < KSTEPS; ++t) {
            const bf16* src;
            if constexpr (CIN == 64) {
                src = uin + (((size_t)idx[t >> 1]) << 6) + ((t & 1) << 5) + quad * 8;
            } else if constexpr (CIN == 32) {
                src = uin + (((size_t)idx[t]) << 5) + quad * 8;
            } else {  // CIN == 16
                constexpr int KS = 9 * 16;
                const int j1 = (2 * t + 1 > 8) ? 8 : 2 * t + 1;
                int r_ = (quad & 2) ? idx[j1] : idx[2 * t];
                if (t * 32 + 24 >= KS) {
                    if (t * 32 + quad * 8 >= KS) r_ = N_VOX;  // tail -> pad row
                }
                src = uin + (((size_t)r_) << 4) + ((quad & 1) << 3);
            }
            a[t] = gload16(src);
        }

        // 3) prefetch next tile's idx (coalesced, stays in flight across MFMA)
        const int tnext = (tile + STRIDE < NTILES) ? tile + STRIDE : tile;
        const int* bn_ = nbr + tnext * 144;
        int i0 = gloadi(bn_ + lane);
        int i1 = gloadi(bn_ + 64 + lane);
        int i2 = gloadi(bn_ + 128 + (lane & 15));

        // 4) wait gathers (3 idx loads remain in flight), compute
        vm_wait3();
#pragma unroll
        for (int t = 0; t < KSTEPS; ++t) pin(a[t]);

        floatx4 acc[NT];
#pragma unroll
        for (int c = 0; c < NT; ++c) acc[c] = (floatx4){0.f, 0.f, 0.f, 0.f};
#pragma unroll
        for (int t = 0; t < KSTEPS; ++t) {
#pragma unroll
            for (int c = 0; c < NT; ++c) {
                const bf16x8 b = BLDS ? Bs[(t * NT + c) * 64 + lane] : Bf[t * NT + c];
                acc[c] = __builtin_amdgcn_mfma_f32_16x16x32_bf16(a[t], b, acc[c], 0, 0, 0);
            }
        }

        // 5) epilogue: lrelu + stats + LDS transpose + coalesced stores
        bf16* tb = tbuf[wave];
#pragma unroll
        for (int c = 0; c < NT; ++c) {
            float ps = 0.f, ps2 = 0.f;
#pragma unroll
            for (int i = 0; i < 4; ++i) {
                float v = acc[c][i];
                v = v > 0.f ? v : 0.01f * v;
                tb[(quad * 4 + i) * COUT + c * 16 + m] = f2b(v);
                ps += v; ps2 += v * v;
            }
            ssum[c] += ps; ssum2[c] += ps2;
        }
#pragma unroll
        for (int g = 0; g < NSTORE; ++g) {
            const int off = g * 512 + lane * 8;
            bf16x8 row = *reinterpret_cast<const bf16x8*>(tb + off);
            gstore16(tout + (size_t)tile * (16 * COUT) + off, row);
        }

        // 6) idx arrived (NSTORE stores still in flight); stash for next iter
        if constexpr (NSTORE == 2) vm_wait2(); else vm_wait1();
        pini(i0); pini(i1); pini(i2);
        int* ibn = idxb[wave][p ^ 1];
        ibn[lane] = i0; ibn[64 + lane] = i1; ibn[128 + (lane & 15)] = i2;
        p ^= 1;
    }

    if constexpr (STATS) {
#pragma unroll
        for (int c = 0; c < NT; ++c) {
            atomicAdd(&sS[c * 16 + m], ssum[c]);
            atomicAdd(&sS2[c * 16 + m], ssum2[c]);
        }
        __syncthreads();
        if (threadIdx.x < COUT) {
            atomicAdd(&stats[threadIdx.x],      sS[threadIdx.x]);
            atomicAdd(&stats[64 + threadIdx.x], sS2[threadIdx.x]);
        }
    }
}

// ---------------------------------------------------------------------------
// In-place BN affine on t[N_VOX,C] (bf16) + zero pad row.
// ---------------------------------------------------------------------------
template<int C>
__global__ __launch_bounds__(256) void bnapply_kernel(
    bf16* t, const float* __restrict__ s,
    const float* __restrict__ g, const float* __restrict__ b)
{
    __shared__ float pa[64], pc[64];
    if (threadIdx.x < C) {
        const float inv_n = 1.0f / N_VOX;
        const float mu = s[threadIdx.x] * inv_n;
        const float var = fmaxf(s[64 + threadIdx.x] * inv_n - mu * mu, 0.f);
        const float a = rsqrtf(var + 1e-5f) * g[threadIdx.x];
        pa[threadIdx.x] = a;
        pc[threadIdx.x] = b[threadIdx.x] - mu * a;
    }
    __syncthreads();
    const int i8 = (blockIdx.x * 256 + threadIdx.x) * 8;
    if (i8 >= (N_VOX + 1) * C) return;
    if (i8 >= N_VOX * C) {
        uint4 z = {0, 0, 0, 0};
        *reinterpret_cast<uint4*>(t + i8) = z;
        return;
    }
    union { bf16x8 v; bf16 e[8]; } U, O;
    U.v = *reinterpret_cast<const bf16x8*>(t + i8);
    const int ch0 = i8 & (C - 1);
#pragma unroll
    for (int j = 0; j < 8; ++j)
        O.e[j] = f2b(pa[ch0 + j] * b2f(U.e[j]) + pc[ch0 + j]);
    *reinterpret_cast<bf16x8*>(t + i8) = O.v;
}

// ---------------------------------------------------------------------------
// out = BN_a(ta) + BN_b(tb); OUT bf16 (+pad row) or float (final).
// ---------------------------------------------------------------------------
template<int C, bool ZROW, typename OUT>
__global__ __launch_bounds__(256) void addbn_kernel(
    const bf16* ta, const float* __restrict__ sa,
    const float* __restrict__ ga, const float* __restrict__ ba,
    const bf16* tb, const float* __restrict__ sb,
    const float* __restrict__ gb, const float* __restrict__ bb,
    OUT* out)
{
    __shared__ float paa[64], pca[64], pab[64], pcb[64];
    if (threadIdx.x < C) {
        const float inv_n = 1.0f / N_VOX;
        const float ma = sa[threadIdx.x] * inv_n;
        const float va = fmaxf(sa[64 + threadIdx.x] * inv_n - ma * ma, 0.f);
        const float aa = rsqrtf(va + 1e-5f) * ga[threadIdx.x];
        paa[threadIdx.x] = aa;
        pca[threadIdx.x] = ba[threadIdx.x] - ma * aa;
        const float mb = sb[threadIdx.x] * inv_n;
        const float vb = fmaxf(sb[64 + threadIdx.x] * inv_n - mb * mb, 0.f);
        const float ab = rsqrtf(vb + 1e-5f) * gb[threadIdx.x];
        pab[threadIdx.x] = ab;
        pcb[threadIdx.x] = bb[threadIdx.x] - mb * ab;
    }
    __syncthreads();
    constexpr int TOTAL = (N_VOX + (ZROW ? 1 : 0)) * C;
    const int i8 = (blockIdx.x * 256 + threadIdx.x) * 8;
    if (i8 >= TOTAL) return;
    if (ZROW && i8 >= N_VOX * C) {
        uint4 z = {0, 0, 0, 0};
        *reinterpret_cast<uint4*>((bf16*)out + i8) = z;
        return;
    }
    union { bf16x8 v; bf16 e[8]; } A, B;
    A.v = *reinterpret_cast<const bf16x8*>(ta + i8);
    B.v = *reinterpret_cast<const bf16x8*>(tb + i8);
    const int ch0 = i8 & (C - 1);
    float r[8];
#pragma unroll
    for (int j = 0; j < 8; ++j)
        r[j] = paa[ch0 + j] * b2f(A.e[j]) + pca[ch0 + j]
             + pab[ch0 + j] * b2f(B.e[j]) + pcb[ch0 + j];
    if constexpr (sizeof(OUT) == 2) {
        union { bf16x8 v; bf16 e[8]; } O;
#pragma unroll
        for (int j = 0; j < 8; ++j) O.e[j] = f2b(r[j]);
        *reinterpret_cast<bf16x8*>(out + i8) = O.v;
    } else {
#pragma unroll
        for (int j = 0; j < 8; ++j) out[i8 + j] = r[j];
    }
}

// ---------------------------------------------------------------------------
// Prep: u0 = bf16(x) + zero pad row; pack 8 f32 weights into bf16 MFMA
// B-fragment order; zero stats; zero pad row of u3.
// ---------------------------------------------------------------------------
#define PACK_TOTAL 139264
__global__ __launch_bounds__(256) void prep_kernel(
    const float* __restrict__ x,
    const float* W0, const float* W1, const float* W2, const float* W3,
    const float* W4, const float* W5, const float* W6, const float* W7,
    bf16* __restrict__ u0, bf16* __restrict__ bpack,
    float* __restrict__ stats, bf16* __restrict__ u3)
{
    const int gid = blockIdx.x * 256 + threadIdx.x;
    constexpr int NXE = (N_VOX + 1) * 16;
    if (gid < NXE) {
        u0[gid] = (gid < N_VOX * 16) ? f2b(x[gid]) : f2b(0.f);
        return;
    }
    int p = gid - NXE;
    if (p < PACK_TOTAL) {
        constexpr int cin[8]  = {16, 32, 16, 32, 32, 64, 32, 64};
        constexpr int cout[8] = {32, 32, 32, 32, 64, 64, 64, 64};
        constexpr int offs[9] = {0, 5120, 14336, 19456, 28672, 47104, 83968, 102400, 139264};
        const float* Ws[8] = {W0, W1, W2, W3, W4, W5, W6, W7};
        int w = 0;
        while (p >= offs[w + 1]) ++w;
        const int e = p - offs[w];
        const int CI = cin[w], CO = cout[w];
        const int NTl = CO / 16;
        const int j = e & 7;
        const int lane = (e >> 3) & 63;
        const int rest = e >> 9;
        const int c = rest % NTl;
        const int t = rest / NTl;
        const int ncol = c * 16 + (lane & 15);
        const int k = t * 32 + (lane >> 4) * 8 + j;
        float val = 0.f;
        if (k < 9 * CI) {
            const int nbq = k / CI;
            const int ci = k % CI;
            val = Ws[w][(nbq * CI + ci) * CO + ncol];
        }
        bpack[p] = f2b(val);
        return;
    }
    p -= PACK_TOTAL;
    if (p < 1024) { stats[p] = 0.f; return; }
    p -= 1024;
    if (p < 32) u3[N_VOX * 32 + p] = f2b(0.f);
}

extern "C" void kernel_launch(void* const* d_in, const int* in_sizes, int n_in,
                              void* d_out, int out_size, void* d_ws, size_t ws_size,
                              hipStream_t stream) {
    const float* x     = (const float*)d_in[0];
    const int* nbr133  = (const int*)d_in[1];
    const int* nbr313  = (const int*)d_in[2];
    const float* W_c1  = (const float*)d_in[3];
    const float* g0    = (const float*)d_in[4];
    const float* b0    = (const float*)d_in[5];
    const float* W_c12 = (const float*)d_in[6];
    const float* g02   = (const float*)d_in[7];
    const float* b02   = (const float*)d_in[8];
    const float* W_c2  = (const float*)d_in[9];
    const float* W_c3  = (const float*)d_in[10];
    const float* g2    = (const float*)d_in[11];
    const float* b2    = (const float*)d_in[12];
    const float* W_r1  = (const float*)d_in[13];
    const float* rg0   = (const float*)d_in[14];
    const float* rb0   = (const float*)d_in[15];
    const float* W_r12 = (const float*)d_in[16];
    const float* rg02  = (const float*)d_in[17];
    const float* rb02  = (const float*)d_in[18];
    const float* W_r2  = (const float*)d_in[19];
    const float* rg1   = (const float*)d_in[20];
    const float* rb1   = (const float*)d_in[21];
    const float* W_r3  = (const float*)d_in[22];
    const float* rg2   = (const float*)d_in[23];
    const float* rb2   = (const float*)d_in[24];

    // Workspace aliasing schedule identical to R3/R5/R6 (correctness-proven).
    char* ws = (char*)d_ws;
    size_t off = 0;
    auto alloc = [&](size_t bytes) -> char* {
        off = (off + 255) & ~(size_t)255;
        char* p = ws + off;
        off += bytes;
        return p;
    };
    const size_t NV = N_VOX;
    bf16* u0   = (bf16*)alloc((NV + 1) * 16 * 2);
    bf16* B1u3 = (bf16*)alloc((NV + 1) * 32 * 2);
    bf16* T4   = (bf16*)alloc(NV * 32 * 2);
    bf16* T2uy = (bf16*)alloc((NV + 1) * 32 * 2);
    bf16* B5B7 = (bf16*)alloc((NV + 1) * 64 * 2);
    bf16* T8   = (bf16*)alloc(NV * 64 * 2);
    bf16* bpack = (bf16*)alloc((size_t)PACK_TOTAL * 2);
    float* stats = (float*)alloc(1024 * 4);
    bf16* T6 = (bf16*)ws;    // alias R0..R2 (19.2 MB available >= 15.36 MB)

    float* st1 = stats + 0 * 128;
    float* st2 = stats + 1 * 128;
    float* st4 = stats + 3 * 128;
    float* st5 = stats + 4 * 128;
    float* st6 = stats + 5 * 128;
    float* st7 = stats + 6 * 128;
    float* st8 = stats + 7 * 128;

    bf16* bp0 = bpack + 0;       // W_c1  (16->32)
    bf16* bp1 = bpack + 5120;    // W_c12 (32->32)
    bf16* bp2 = bpack + 14336;   // W_c2  (16->32)
    bf16* bp3 = bpack + 19456;   // W_c3  (32->32)
    bf16* bp4 = bpack + 28672;   // W_r1  (32->64)
    bf16* bp5 = bpack + 47104;   // W_r12 (64->64)
    bf16* bp6 = bpack + 83968;   // W_r2  (32->64)
    bf16* bp7 = bpack + 102400;  // W_r3  (64->64)

    const int prep_total = (N_VOX + 1) * 16 + PACK_TOTAL + 1024 + 32;
    prep_kernel<<<(prep_total + 255) / 256, 256, 0, stream>>>(
        x, W_c1, W_c12, W_c2, W_c3, W_r1, W_r12, W_r2, W_r3, u0, bpack, stats, B1u3);

    const int E32 = (((N_VOX + 1) * 32) / 8 + 255) / 256;
    const int E64 = (((N_VOX + 1) * 64) / 8 + 255) / 256;

    // ResContextBlock
    conv_kernel<16, 32, 4, true><<<768, 256, 0, stream>>>(u0, nbr133, bp0, B1u3, st1);
    bnapply_kernel<32><<<E32, 256, 0, stream>>>(B1u3, st1, g0, b0);
    conv_kernel<32, 32, 4, true><<<768, 256, 0, stream>>>(B1u3, nbr313, bp1, T2uy, st2);
    conv_kernel<16, 32, 4, false><<<768, 256, 0, stream>>>(u0, nbr313, bp2, B1u3, nullptr);
    conv_kernel<32, 32, 4, true><<<768, 256, 0, stream>>>(B1u3, nbr133, bp3, T4, st4);
    addbn_kernel<32, true, bf16><<<E32, 256, 0, stream>>>(
        T2uy, st2, g02, b02, T4, st4, g2, b2, T2uy);
    // ResBlock
    conv_kernel<32, 64, 8, true><<<512, 512, 0, stream>>>(T2uy, nbr313, bp4, B5B7, st5);
    bnapply_kernel<64><<<E64, 256, 0, stream>>>(B5B7, st5, rg0, rb0);
    conv_kernel<64, 64, 8, true><<<256, 512, 0, stream>>>(B5B7, nbr133, bp5, T6, st6);
    conv_kernel<32, 64, 8, true><<<512, 512, 0, stream>>>(T2uy, nbr133, bp6, B5B7, st7);
    bnapply_kernel<64><<<E64, 256, 0, stream>>>(B5B7, st7, rg1, rb1);
    conv_kernel<64, 64, 8, true><<<256, 512, 0, stream>>>(B5B7, nbr313, bp7, T8, st8);
    addbn_kernel<64, false, float><<<((N_VOX * 64 / 8) + 255) / 256, 256, 0, stream>>>(
        T6, st6, rg02, rb02, T8, st8, rg2, rb2, (float*)d_out);
}